// Round 2
// baseline (9118.172 us; speedup 1.0000x reference)
//
#include <hip/hip_runtime.h>
#include <hip/hip_bf16.h>
#include <math.h>

#define DM 1024
#define NH 16
#define HD 64
#define BB 2
#define TT 2048
#define MROWS (BB*TT)   // 4096

typedef __hip_bfloat16 bf16;

// ---------------------------------------------------------------------------
// Runtime input-dtype probe. Interprets the first 512 halfwords of x as bf16
// and counts exponents in the plausible N(0,1) band [2^-10, 16).
//  - true bf16 data: ~512/512 in band
//  - fp32 data misread as bf16: odd halves (float high bits) pass, even
//    halves are ~uniform mantissa bits (~5% pass) -> ~270/512
// flag = 1 means inputs are fp32, 0 means bf16. Deterministic, graph-safe.
// ---------------------------------------------------------------------------
__global__ void detect_dtype(const unsigned short* __restrict__ x, int* flag) {
    __shared__ int cnt;
    if (threadIdx.x == 0) cnt = 0;
    __syncthreads();
    int local = 0;
    for (int i = threadIdx.x; i < 512; i += 256) {
        unsigned short u = x[i];
        int e = (u >> 7) & 0xFF;
        if (e >= 117 && e <= 130) local++;
    }
    atomicAdd(&cnt, local);
    __syncthreads();
    if (threadIdx.x == 0) *flag = (cnt >= 384) ? 0 : 1;
}

__device__ __forceinline__ float ldin(const void* p, size_t i, int f32) {
    return f32 ? ((const float*)p)[i]
               : __bfloat162float(((const bf16*)p)[i]);
}

// ---------------------------------------------------------------------------
// GEMM: Y[M,N] (f32) = A[M,K] * W[N,K]^T, K = N = DM. A/W dtype per *flag.
// ---------------------------------------------------------------------------
__global__ void gemm_in_f32(const void* __restrict__ A,
                            const void* __restrict__ W,
                            float* __restrict__ Y,
                            const int* __restrict__ flag) {
    const int f32 = *flag;
    __shared__ float As[16][17];
    __shared__ float Ws[16][17];
    const int tx = threadIdx.x, ty = threadIdx.y;
    const int n = blockIdx.x * 16 + tx;
    const int m = blockIdx.y * 16 + ty;
    float acc = 0.f;
    for (int k0 = 0; k0 < DM; k0 += 16) {
        As[ty][tx] = ldin(A, (size_t)(blockIdx.y * 16 + ty) * DM + k0 + tx, f32);
        Ws[ty][tx] = ldin(W, (size_t)(blockIdx.x * 16 + ty) * DM + k0 + tx, f32);
        __syncthreads();
#pragma unroll
        for (int kk = 0; kk < 16; kk++)
            acc += As[ty][kk] * Ws[tx][kk];
        __syncthreads();
    }
    Y[(size_t)m * DM + n] = acc;
}

// Final projection: A is f32 workspace, W and output dtype per *flag.
__global__ void gemm_f32_out(const float* __restrict__ A,
                             const void* __restrict__ W,
                             void* __restrict__ Y,
                             const int* __restrict__ flag) {
    const int f32 = *flag;
    __shared__ float As[16][17];
    __shared__ float Ws[16][17];
    const int tx = threadIdx.x, ty = threadIdx.y;
    const int n = blockIdx.x * 16 + tx;
    const int m = blockIdx.y * 16 + ty;
    float acc = 0.f;
    for (int k0 = 0; k0 < DM; k0 += 16) {
        As[ty][tx] = A[(size_t)(blockIdx.y * 16 + ty) * DM + k0 + tx];
        Ws[ty][tx] = ldin(W, (size_t)(blockIdx.x * 16 + ty) * DM + k0 + tx, f32);
        __syncthreads();
#pragma unroll
        for (int kk = 0; kk < 16; kk++)
            acc += As[ty][kk] * Ws[tx][kk];
        __syncthreads();
    }
    if (f32) ((float*)Y)[(size_t)m * DM + n] = acc;
    else     ((bf16*)Y)[(size_t)m * DM + n] = __float2bfloat16(acc);
}

// ---------------------------------------------------------------------------
// RoPE in-place on Q and K, layout [B*T, DM] (heads packed in cols).
// ---------------------------------------------------------------------------
__global__ void rope_kernel(float* __restrict__ Q, float* __restrict__ K) {
    const size_t idx = (size_t)blockIdx.x * blockDim.x + threadIdx.x;
    const size_t total = (size_t)MROWS * (DM / 2);
    if (idx >= total) return;
    const int pair = (int)(idx % (DM / 2));
    const size_t row = idx / (DM / 2);
    const int t = (int)(row % TT);
    const int i = pair % (HD / 2);
    const float inv_freq = powf(10000.0f, -2.0f * (float)i / (float)HD);
    const float ang = (float)t * inv_freq;
    const float c = cosf(ang), s = sinf(ang);
    const size_t base = row * DM + (size_t)pair * 2;

    float q1 = Q[base], q2 = Q[base + 1];
    Q[base]     = q1 * c - q2 * s;
    Q[base + 1] = q1 * s + q2 * c;

    float k1 = K[base], k2 = K[base + 1];
    K[base]     = k1 * c - k2 * s;
    K[base + 1] = k1 * s + k2 * c;
}

// ---------------------------------------------------------------------------
// Attention: one block (256 threads) per (b, h, q-row). Scores in LDS.
// ---------------------------------------------------------------------------
__global__ void attn_kernel(const float* __restrict__ Q,
                            const float* __restrict__ K,
                            const float* __restrict__ V,
                            float* __restrict__ O) {
    const int t = blockIdx.x;
    const int h = blockIdx.y;
    const int b = blockIdx.z;
    const int tid = threadIdx.x;
    const int lane = tid & 63;
    const int wid = tid >> 6;

    __shared__ __align__(16) float qv[HD];
    __shared__ float sc[TT];
    __shared__ float part[4][HD];
    __shared__ float tmpmax[4];
    __shared__ float tmpsum[4];

    const size_t qrow_off = ((size_t)(b * TT + t)) * DM + h * HD;
    if (tid < HD) qv[tid] = Q[qrow_off + tid];
    __syncthreads();

    const int nk = t + 1;
    const float scale = 0.125f;

    for (int k = tid; k < nk; k += 256) {
        const float4* kr = (const float4*)(K + ((size_t)(b * TT + k)) * DM + h * HD);
        const float4* qr = (const float4*)qv;
        float acc = 0.f;
#pragma unroll
        for (int d4 = 0; d4 < HD / 4; d4++) {
            float4 kk = kr[d4];
            float4 qq = qr[d4];
            acc += qq.x * kk.x + qq.y * kk.y + qq.z * kk.z + qq.w * kk.w;
        }
        sc[k] = acc * scale;
    }
    __syncthreads();

    float m = -INFINITY;
    for (int k = tid; k < nk; k += 256) m = fmaxf(m, sc[k]);
#pragma unroll
    for (int o = 32; o > 0; o >>= 1) m = fmaxf(m, __shfl_down(m, o));
    if (lane == 0) tmpmax[wid] = m;
    __syncthreads();
    m = fmaxf(fmaxf(tmpmax[0], tmpmax[1]), fmaxf(tmpmax[2], tmpmax[3]));

    float ssum = 0.f;
    for (int k = tid; k < nk; k += 256) {
        float e = expf(sc[k] - m);
        sc[k] = e;
        ssum += e;
    }
#pragma unroll
    for (int o = 32; o > 0; o >>= 1) ssum += __shfl_down(ssum, o);
    if (lane == 0) tmpsum[wid] = ssum;
    __syncthreads();
    const float inv = 1.f / (tmpsum[0] + tmpsum[1] + tmpsum[2] + tmpsum[3]);

    float acc = 0.f;
    for (int k = wid; k < nk; k += 4)
        acc += sc[k] * V[((size_t)(b * TT + k)) * DM + h * HD + lane];
    part[wid][lane] = acc;
    __syncthreads();
    if (wid == 0) {
        float r = part[0][lane] + part[1][lane] + part[2][lane] + part[3][lane];
        O[((size_t)(b * TT + t)) * DM + h * HD + lane] = r * inv;
    }
}

// ---------------------------------------------------------------------------
extern "C" void kernel_launch(void* const* d_in, const int* in_sizes, int n_in,
                              void* d_out, int out_size, void* d_ws, size_t ws_size,
                              hipStream_t stream) {
    const void* x  = d_in[0];
    const void* wq = d_in[1];
    const void* wk = d_in[2];
    const void* wv = d_in[3];
    const void* wo = d_in[4];
    // d_in[5] = token_pos, unused by the reference computation

    const size_t mat = (size_t)MROWS * DM;          // 4M elements
    float* Q  = (float*)d_ws;
    float* Kp = Q  + mat;
    float* Vp = Kp + mat;
    float* Ao = Vp + mat;                           // 64 MB total
    int* flag = (int*)((char*)d_ws + mat * 4 * sizeof(float));  // past the matrices

    detect_dtype<<<1, 256, 0, stream>>>((const unsigned short*)x, flag);

    dim3 gblk(16, 16);
    dim3 ggrid(DM / 16, MROWS / 16);

    gemm_in_f32<<<ggrid, gblk, 0, stream>>>(x, wq, Q, flag);
    gemm_in_f32<<<ggrid, gblk, 0, stream>>>(x, wk, Kp, flag);
    gemm_in_f32<<<ggrid, gblk, 0, stream>>>(x, wv, Vp, flag);

    const size_t rope_threads = (size_t)MROWS * (DM / 2);
    rope_kernel<<<(unsigned)((rope_threads + 255) / 256), 256, 0, stream>>>(Q, Kp);

    attn_kernel<<<dim3(TT, NH, BB), 256, 0, stream>>>(Q, Kp, Vp, Ao);

    gemm_f32_out<<<ggrid, gblk, 0, stream>>>(Ao, wo, d_out, flag);
}

// Round 3
// 2269.256 us; speedup vs baseline: 4.0181x; 4.0181x over previous
//
#include <hip/hip_runtime.h>
#include <hip/hip_bf16.h>
#include <math.h>

#define DM 1024
#define NH 16
#define HD 64
#define BB 2
#define TT 2048
#define MROWS (BB*TT)   // 4096
#define TQ 64
#define TK 64

typedef __hip_bfloat16 bf16;

// ---------------------------------------------------------------------------
// Runtime input-dtype probe (flag=1 -> fp32 inputs, 0 -> bf16). Graph-safe.
// ---------------------------------------------------------------------------
__global__ void detect_dtype(const unsigned short* __restrict__ x, int* flag) {
    __shared__ int cnt;
    if (threadIdx.x == 0) cnt = 0;
    __syncthreads();
    int local = 0;
    for (int i = threadIdx.x; i < 512; i += 256) {
        unsigned short u = x[i];
        int e = (u >> 7) & 0xFF;
        if (e >= 117 && e <= 130) local++;
    }
    atomicAdd(&cnt, local);
    __syncthreads();
    if (threadIdx.x == 0) *flag = (cnt >= 384) ? 0 : 1;
}

__device__ __forceinline__ float4 ld4(const void* p, size_t i, int f32) {
    if (f32) return *(const float4*)((const float*)p + i);
    const bf16* q = (const bf16*)p + i;
    return make_float4(__bfloat162float(q[0]), __bfloat162float(q[1]),
                       __bfloat162float(q[2]), __bfloat162float(q[3]));
}

// ---------------------------------------------------------------------------
// GEMM Y[M,N] = A[M,K] * W[N,K]^T.  64x64 block tile, BK=32, 4x4 reg tile.
// LDS stride 44 floats (176B, 16B-aligned, 2-way-only bank alias = free).
// ---------------------------------------------------------------------------
#define GST 44

__global__ __launch_bounds__(256) void gemm_in(const void* __restrict__ A,
                                               const void* __restrict__ W,
                                               float* __restrict__ Y,
                                               const int* __restrict__ flag) {
    const int f32 = *flag;
    __shared__ float As[64][GST];
    __shared__ float Ws[64][GST];
    const int tx = threadIdx.x, ty = threadIdx.y;
    const int tid = ty * 16 + tx;
    const int m0 = blockIdx.y * 64, n0 = blockIdx.x * 64;
    float acc[4][4] = {};
    for (int k0 = 0; k0 < DM; k0 += 32) {
        for (int u = tid; u < 64 * 8; u += 256) {   // 64 rows x 8 float4
            const int r = u >> 3, c4 = u & 7;
            *(float4*)&As[r][c4 * 4] = ld4(A, (size_t)(m0 + r) * DM + k0 + c4 * 4, f32);
            *(float4*)&Ws[r][c4 * 4] = ld4(W, (size_t)(n0 + r) * DM + k0 + c4 * 4, f32);
        }
        __syncthreads();
        for (int k4 = 0; k4 < 8; k4++) {
            float a[4][4], bw[4][4];
#pragma unroll
            for (int r = 0; r < 4; r++) *(float4*)a[r] = *(const float4*)&As[ty * 4 + r][k4 * 4];
#pragma unroll
            for (int c = 0; c < 4; c++) *(float4*)bw[c] = *(const float4*)&Ws[tx * 4 + c][k4 * 4];
#pragma unroll
            for (int kk = 0; kk < 4; kk++)
#pragma unroll
                for (int r = 0; r < 4; r++)
#pragma unroll
                    for (int c = 0; c < 4; c++)
                        acc[r][c] += a[r][kk] * bw[c][kk];
        }
        __syncthreads();
    }
#pragma unroll
    for (int r = 0; r < 4; r++)
        *(float4*)(Y + (size_t)(m0 + ty * 4 + r) * DM + n0 + tx * 4) = *(float4*)acc[r];
}

// Final projection: A f32 workspace, W/out dtype per flag.
__global__ void __launch_bounds__(256) gemm_out(const float* __restrict__ A,
                                                const void* __restrict__ W,
                                                void* __restrict__ Y,
                                                const int* __restrict__ flag) {
    const int f32 = *flag;
    __shared__ float As[64][GST];
    __shared__ float Ws[64][GST];
    const int tx = threadIdx.x, ty = threadIdx.y;
    const int tid = ty * 16 + tx;
    const int m0 = blockIdx.y * 64, n0 = blockIdx.x * 64;
    float acc[4][4] = {};
    for (int k0 = 0; k0 < DM; k0 += 32) {
        for (int u = tid; u < 64 * 8; u += 256) {
            const int r = u >> 3, c4 = u & 7;
            *(float4*)&As[r][c4 * 4] = *(const float4*)(A + (size_t)(m0 + r) * DM + k0 + c4 * 4);
            *(float4*)&Ws[r][c4 * 4] = ld4(W, (size_t)(n0 + r) * DM + k0 + c4 * 4, f32);
        }
        __syncthreads();
        for (int k4 = 0; k4 < 8; k4++) {
            float a[4][4], bw[4][4];
#pragma unroll
            for (int r = 0; r < 4; r++) *(float4*)a[r] = *(const float4*)&As[ty * 4 + r][k4 * 4];
#pragma unroll
            for (int c = 0; c < 4; c++) *(float4*)bw[c] = *(const float4*)&Ws[tx * 4 + c][k4 * 4];
#pragma unroll
            for (int kk = 0; kk < 4; kk++)
#pragma unroll
                for (int r = 0; r < 4; r++)
#pragma unroll
                    for (int c = 0; c < 4; c++)
                        acc[r][c] += a[r][kk] * bw[c][kk];
        }
        __syncthreads();
    }
#pragma unroll
    for (int r = 0; r < 4; r++) {
        const size_t o = (size_t)(m0 + ty * 4 + r) * DM + n0 + tx * 4;
        if (f32) {
            *(float4*)((float*)Y + o) = *(float4*)acc[r];
        } else {
            bf16* y = (bf16*)Y + o;
#pragma unroll
            for (int c = 0; c < 4; c++) y[c] = __float2bfloat16(acc[r][c]);
        }
    }
}

// ---------------------------------------------------------------------------
// RoPE in-place on Q and K, layout [B*T, DM].
// ---------------------------------------------------------------------------
__global__ void rope_kernel(float* __restrict__ Q, float* __restrict__ K) {
    const size_t idx = (size_t)blockIdx.x * blockDim.x + threadIdx.x;
    const size_t total = (size_t)MROWS * (DM / 2);
    if (idx >= total) return;
    const int pair = (int)(idx % (DM / 2));
    const size_t row = idx / (DM / 2);
    const int t = (int)(row % TT);
    const int i = pair % (HD / 2);
    const float inv_freq = powf(10000.0f, -2.0f * (float)i / (float)HD);
    const float ang = (float)t * inv_freq;
    const float c = cosf(ang), s = sinf(ang);
    const size_t base = row * DM + (size_t)pair * 2;
    float q1 = Q[base], q2 = Q[base + 1];
    Q[base]     = q1 * c - q2 * s;
    Q[base + 1] = q1 * s + q2 * c;
    float k1 = K[base], k2 = K[base + 1];
    K[base]     = k1 * c - k2 * s;
    K[base + 1] = k1 * s + k2 * c;
}

// ---------------------------------------------------------------------------
// Flash attention: block = (16,16) threads, one (b, h, 64-row q-tile) each.
// K/V 64-row tiles staged in LDS; S/P/O as 4x4 register fragments; online
// softmax with 16-lane shuffle row reductions. P reuses the K LDS buffer.
// LDS stride 68 floats (272B, 16B-aligned; 2-way alias only = free).
// ---------------------------------------------------------------------------
#define FST 68

__global__ void __launch_bounds__(256) flash_attn(const float* __restrict__ Q,
                                                  const float* __restrict__ K,
                                                  const float* __restrict__ V,
                                                  float* __restrict__ O) {
    const int qt = blockIdx.x;
    const int h  = blockIdx.y;
    const int b  = blockIdx.z;
    const int tx = threadIdx.x, ty = threadIdx.y;
    const int tid = ty * 16 + tx;

    __shared__ float Qs[TQ][FST];
    __shared__ float KPs[TK][FST];   // K tile, reused as P tile
    __shared__ float Vs[TK][FST];

    const size_t base_bh = (size_t)(b * TT) * DM + h * HD;

    // load Q tile (64 rows x 16 float4)
    for (int u = tid; u < TQ * 16; u += 256) {
        const int r = u >> 4, d4 = u & 15;
        *(float4*)&Qs[r][d4 * 4] =
            *(const float4*)(Q + base_bh + (size_t)(qt * TQ + r) * DM + d4 * 4);
    }

    float o[4][4] = {};
    float mrow[4], lrow[4];
#pragma unroll
    for (int r = 0; r < 4; r++) { mrow[r] = -INFINITY; lrow[r] = 0.f; }

    for (int kt = 0; kt <= qt; kt++) {
        __syncthreads();   // previous iteration's KPs/Vs readers done (also orders Qs load)
        for (int u = tid; u < TK * 16; u += 256) {
            const int r = u >> 4, d4 = u & 15;
            const size_t g = base_bh + (size_t)(kt * TK + r) * DM + d4 * 4;
            *(float4*)&KPs[r][d4 * 4] = *(const float4*)(K + g);
            *(float4*)&Vs[r][d4 * 4]  = *(const float4*)(V + g);
        }
        __syncthreads();

        // S = Q * K^T fragment (rows ty*4+r, cols tx*4+c)
        float s[4][4] = {};
        for (int d4 = 0; d4 < HD / 4; d4++) {
            float a[4][4], kk[4][4];
#pragma unroll
            for (int r = 0; r < 4; r++) *(float4*)a[r] = *(const float4*)&Qs[ty * 4 + r][d4 * 4];
#pragma unroll
            for (int c = 0; c < 4; c++) *(float4*)kk[c] = *(const float4*)&KPs[tx * 4 + c][d4 * 4];
#pragma unroll
            for (int dd = 0; dd < 4; dd++)
#pragma unroll
                for (int r = 0; r < 4; r++)
#pragma unroll
                    for (int c = 0; c < 4; c++)
                        s[r][c] += a[r][dd] * kk[c][dd];
        }
#pragma unroll
        for (int r = 0; r < 4; r++)
#pragma unroll
            for (int c = 0; c < 4; c++)
                s[r][c] *= 0.125f;   // 1/sqrt(64)
        if (kt == qt) {
#pragma unroll
            for (int r = 0; r < 4; r++)
#pragma unroll
                for (int c = 0; c < 4; c++)
                    if (tx * 4 + c > ty * 4 + r) s[r][c] = -INFINITY;
        }

        // online softmax per q-row (row owned by the 16 tx lanes of one ty)
        float p[4][4];
#pragma unroll
        for (int r = 0; r < 4; r++) {
            float mx = fmaxf(fmaxf(s[r][0], s[r][1]), fmaxf(s[r][2], s[r][3]));
#pragma unroll
            for (int off = 8; off; off >>= 1) mx = fmaxf(mx, __shfl_xor(mx, off));
            const float mnew = fmaxf(mrow[r], mx);
            const float alpha = __expf(mrow[r] - mnew);
            float psum = 0.f;
#pragma unroll
            for (int c = 0; c < 4; c++) { p[r][c] = __expf(s[r][c] - mnew); psum += p[r][c]; }
#pragma unroll
            for (int off = 8; off; off >>= 1) psum += __shfl_xor(psum, off);
            mrow[r] = mnew;
            lrow[r] = lrow[r] * alpha + psum;
#pragma unroll
            for (int c = 0; c < 4; c++) o[r][c] *= alpha;
        }

        __syncthreads();   // all KPs (K) readers done before overwriting with P
#pragma unroll
        for (int r = 0; r < 4; r++)
            *(float4*)&KPs[ty * 4 + r][tx * 4] = *(float4*)p[r];
        __syncthreads();

        // O += P * V  (cols = head dims tx*4+c)
        for (int k4 = 0; k4 < TK / 4; k4++) {
            float pp[4][4], vv[4][4];
#pragma unroll
            for (int r = 0; r < 4; r++) *(float4*)pp[r] = *(const float4*)&KPs[ty * 4 + r][k4 * 4];
#pragma unroll
            for (int j = 0; j < 4; j++) *(float4*)vv[j] = *(const float4*)&Vs[k4 * 4 + j][tx * 4];
#pragma unroll
            for (int r = 0; r < 4; r++)
#pragma unroll
                for (int c = 0; c < 4; c++)
                    o[r][c] += pp[r][0] * vv[0][c] + pp[r][1] * vv[1][c]
                             + pp[r][2] * vv[2][c] + pp[r][3] * vv[3][c];
        }
    }

    // normalize + store
#pragma unroll
    for (int r = 0; r < 4; r++) {
        const float inv = 1.f / lrow[r];
        float4 res = make_float4(o[r][0] * inv, o[r][1] * inv, o[r][2] * inv, o[r][3] * inv);
        *(float4*)(O + base_bh + (size_t)(qt * TQ + ty * 4 + r) * DM + tx * 4) = res;
    }
}

// ---------------------------------------------------------------------------
extern "C" void kernel_launch(void* const* d_in, const int* in_sizes, int n_in,
                              void* d_out, int out_size, void* d_ws, size_t ws_size,
                              hipStream_t stream) {
    const void* x  = d_in[0];
    const void* wq = d_in[1];
    const void* wk = d_in[2];
    const void* wv = d_in[3];
    const void* wo = d_in[4];

    const size_t mat = (size_t)MROWS * DM;
    float* Q  = (float*)d_ws;
    float* Kp = Q  + mat;
    float* Vp = Kp + mat;
    float* Ao = Vp + mat;
    int* flag = (int*)((char*)d_ws + mat * 4 * sizeof(float));

    detect_dtype<<<1, 256, 0, stream>>>((const unsigned short*)x, flag);

    dim3 gblk(16, 16);
    dim3 ggrid(DM / 64, MROWS / 64);

    gemm_in<<<ggrid, gblk, 0, stream>>>(x, wq, Q, flag);
    gemm_in<<<ggrid, gblk, 0, stream>>>(x, wk, Kp, flag);
    gemm_in<<<ggrid, gblk, 0, stream>>>(x, wv, Vp, flag);

    const size_t rope_threads = (size_t)MROWS * (DM / 2);
    rope_kernel<<<(unsigned)((rope_threads + 255) / 256), 256, 0, stream>>>(Q, Kp);

    flash_attn<<<dim3(TT / TQ, NH, BB), gblk, 0, stream>>>(Q, Kp, Vp, Ao);

    gemm_out<<<ggrid, gblk, 0, stream>>>(Ao, wo, d_out, flag);
}